// Round 14
// baseline (3750.037 us; speedup 1.0000x reference)
//
#include <hip/hip_runtime.h>
#include <cmath>
#include <cstring>
#include <cstdint>
#include <vector>

#define TPB 256
static constexpr int kLMAX = 32;
static constexpr int kNMN  = 43680;   // sum_{l<32} (2l+1)^2
static constexpr int kNM   = 1024;    // sum_{l<32} (2l+1)
static constexpr int kB    = 2;
static constexpr int kF0   = 3, kF1 = 60, kF2 = 36;
static constexpr int kCube = 262144;  // 64^3
static constexpr int kFCH  = 24;      // plane chunk

__host__ __device__ inline int off3i(int l) { return l * (4 * l * l - 1) / 3; }

// ---------------------------------------------------------------------------
// Host-side constant tables (~2.9 MB seeds; d_b = F_{b&7} * G_{b>>3}).
// ---------------------------------------------------------------------------
static void h_matmul(const std::vector<double>& A, const std::vector<double>& B,
                     std::vector<double>& C, int n) {
    C.assign((size_t)n * n, 0.0);
    for (int i = 0; i < n; i++)
        for (int k = 0; k < n; k++) {
            double a = A[(size_t)i * n + k];
            if (a == 0.0) continue;
            const double* bp = &B[(size_t)k * n];
            double* cp = &C[(size_t)i * n];
            for (int j = 0; j < n; j++) cp[j] += a * bp[j];
        }
}

struct HostTables {
    std::vector<float> blob;
    size_t o_twf, o_twi, o_w, o_lmnl, o_lml, o_etab;
    size_t bytes;
    HostTables() {
        size_t n = 0;
        o_twf = n;  n += 128;
        o_twi = n;  n += 128;
        o_w = n;    n += 64;
        o_lmnl = n; n += kNMN;
        o_lml = n;  n += kNM;
        o_etab = n; n += (size_t)16 * kNMN;    // [F_0..F_7, G_0..G_7] per l
        blob.assign(n, 0.0f);
        bytes = n * 4;

        for (int k = 0; k < 64; k++) {
            double th = -2.0 * M_PI * k / 64.0;
            blob[o_twf + 2 * k]     = (float)cos(th);
            blob[o_twf + 2 * k + 1] = (float)sin(th);
            blob[o_twi + 2 * k]     = (float)cos(th);
            blob[o_twi + 2 * k + 1] = (float)(-sin(th));
        }
        for (int j = 0; j < 64; j++) {
            double s = 0;
            for (int k = 0; k < 32; k++)
                s += sin((2.0 * j + 1) * (2.0 * k + 1) * M_PI / 128.0) / (2.0 * k + 1);
            blob[o_w + j] = (float)(2.0 / 32.0 * sin(M_PI * (2.0 * j + 1) / 128.0) * s);
        }
        std::vector<double> A, Eh, E0, E08, F, G, term, tmp;
        for (int l = 0; l < kLMAX; l++) {
            int R = 2 * l + 1, o3 = off3i(l);
            A.assign((size_t)R * R, 0.0);
            for (int i = 0; i + 1 < R; i++) {
                double m = (double)i - l;
                double c = sqrt((double)l * (l + 1) - m * (m + 1));
                A[(size_t)(i + 1) * R + i] = -(M_PI / 128.0) * c * 0.5;
                A[(size_t)i * R + (i + 1)] =  (M_PI / 128.0) * c * 0.5;
            }
            Eh.assign((size_t)R * R, 0.0);
            for (int i = 0; i < R; i++) Eh[(size_t)i * R + i] = 1.0;
            term = Eh;
            for (int k = 1; k <= 30; k++) {
                h_matmul(term, A, tmp, R);
                for (auto& v : tmp) v /= k;
                term = tmp;
                for (size_t i = 0; i < (size_t)R * R; i++) Eh[i] += term[i];
            }
            h_matmul(Eh, Eh, E0, R);
            h_matmul(E0, E0, tmp, R);
            h_matmul(tmp, tmp, E08, R);
            h_matmul(E08, E08, tmp, R); E08 = tmp;  // E0^8
            F = Eh;
            for (int lo = 0; lo < 8; lo++) {
                for (int r = 0; r < R * R; r++)
                    blob[o_etab + (size_t)lo * kNMN + o3 + r] = (float)F[r];
                if (lo < 7) { h_matmul(F, E0, tmp, R); F = tmp; }
            }
            G.assign((size_t)R * R, 0.0);
            for (int i = 0; i < R; i++) G[(size_t)i * R + i] = 1.0;
            for (int hi = 0; hi < 8; hi++) {
                for (int r = 0; r < R * R; r++)
                    blob[o_etab + (size_t)(8 + hi) * kNMN + o3 + r] = (float)G[r];
                if (hi < 7) { h_matmul(G, E08, tmp, R); G = tmp; }
            }
            int32_t li = l;
            for (int r = 0; r < R * R; r++) memcpy(&blob[o_lmnl + o3 + r], &li, 4);
            for (int m = 0; m < R; m++)    memcpy(&blob[o_lml + (size_t)l * l + m], &li, 4);
        }
    }
};
static HostTables g_tab;

// ---------------------------------------------------------------------------
__global__ __launch_bounds__(TPB) void k_gendqA(const float* __restrict__ etab,
                                                float* __restrict__ dtmp) {
    __shared__ float Fm[3969];
    __shared__ float Gm[63 * 64];
    int l = blockIdx.x >> 6, b = blockIdx.x & 63;
    int lo = b & 7, hi = b >> 3;
    int R = 2 * l + 1, RR = R * R, o3 = off3i(l);
    int tid = threadIdx.x;
    const float* Fsrc = etab + (size_t)lo * kNMN + o3;
    const float* Gsrc = etab + (size_t)(8 + hi) * kNMN + o3;
    for (int i = tid; i < RR; i += TPB) Fm[i] = Fsrc[i];
    for (int i = tid; i < R * 64; i += TPB) {
        int k = i >> 6, c = i & 63;
        Gm[i] = (c < R) ? Gsrc[k * R + c] : 0.f;
    }
    __syncthreads();
    int Gc = (R + 15) >> 4;
    if (tid < R * Gc) {
        int row = tid / Gc, g = tid - row * Gc;
        float4 A0 = make_float4(0,0,0,0), A1 = A0, A2 = A0, A3 = A0;
        const float* fr = Fm + row * R;
        for (int k = 0; k < R; k++) {
            float a = fr[k];
            const float4* gp = (const float4*)(Gm + (k << 6) + (g << 4));
            float4 q0 = gp[0], q1 = gp[1], q2 = gp[2], q3 = gp[3];
            A0.x += a * q0.x; A0.y += a * q0.y; A0.z += a * q0.z; A0.w += a * q0.w;
            A1.x += a * q1.x; A1.y += a * q1.y; A1.z += a * q1.z; A1.w += a * q1.w;
            A2.x += a * q2.x; A2.y += a * q2.y; A2.z += a * q2.z; A2.w += a * q2.w;
            A3.x += a * q3.x; A3.y += a * q3.y; A3.z += a * q3.z; A3.w += a * q3.w;
        }
        float v[16] = {A0.x,A0.y,A0.z,A0.w, A1.x,A1.y,A1.z,A1.w,
                       A2.x,A2.y,A2.z,A2.w, A3.x,A3.y,A3.z,A3.w};
        float* dst = dtmp + (size_t)o3 * 64 + (size_t)b * RR + row * R;
        int c0 = g << 4;
        #pragma unroll
        for (int e = 0; e < 16; e++)
            if (c0 + e < R) dst[c0 + e] = v[e];
    }
}

__global__ __launch_bounds__(TPB) void k_scat(const float* __restrict__ dtmp,
                                              const float* __restrict__ w,
                                              float* __restrict__ dqz,
                                              float* __restrict__ dqtw) {
    __shared__ float S[64 * 65];
    int l = blockIdx.x / 63, tile = blockIdx.x % 63;
    int R = 2 * l + 1, RR = R * R, o3 = off3i(l);
    int i0 = tile * 64;
    if (i0 >= RR) return;
    int tid = threadIdx.x;
    const float* src = dtmp + (size_t)o3 * 64;
    #pragma unroll
    for (int s = 0; s < 16; s++) {
        int idx = tid + s * TPB;
        int b = idx >> 6, ii = idx & 63;
        int i = i0 + ii;
        S[ii * 65 + b] = (i < RR) ? src[(size_t)b * RR + i] : 0.f;
    }
    __syncthreads();
    float Rf = (float)R;
    #pragma unroll
    for (int s = 0; s < 16; s++) {
        int idx = tid + s * TPB;
        int ii = idx >> 6, b = idx & 63;
        int i = i0 + ii;
        if (i < RR) {
            float v = S[ii * 65 + b];
            dqtw[((size_t)o3 + i) * 64 + b] = w[b] * v;
            int mi = i / R, ni = i - mi * R;
            int nu = (ni - l) & 63;
            dqz[((size_t)(l * l + mi) * 64 + nu) * 64 + b] = Rf * v;
        }
    }
}

__global__ void k_transde(const float* __restrict__ dehalf, float* __restrict__ deT,
                          const int* __restrict__ lmn_l) {
    int t = blockIdx.x * TPB + threadIdx.x;
    if (t >= kNMN) return;
    int l = lmn_l[t], o3 = off3i(l), r = t - o3, R = 2 * l + 1;
    int n = r / R, k = r - n * R;
    deT[o3 + k * R + n] = dehalf[t];
}

__global__ void k_khat(const float* __restrict__ kern, float2* __restrict__ khat,
                       const float2* __restrict__ twf, int total, float scale) {
    int t = blockIdx.x * TPB + threadIdx.x;
    if (t >= total) return;
    int nu = t & 63, fo = t >> 6;
    const float* row = kern + (size_t)fo * 64;
    float re = 0, im = 0;
    for (int p = 0; p < 64; p++) {
        float2 w = twf[(p * nu) & 63];
        float v = row[p];
        re += v * w.x; im += v * w.y;
    }
    khat[t] = make_float2(re * scale, im * scale);
}

__global__ void k_fft1(const float* __restrict__ x, float2* __restrict__ xf1,
                       const float2* __restrict__ twf) {
    int t = blockIdx.x * TPB + threadIdx.x;
    if (t >= kB * kF0 * 64 * 64) return;
    int mu = t & 63, row = t >> 6;
    const float* p = x + (size_t)row * 64;
    float re = 0, im = 0;
    for (int a = 0; a < 64; a++) {
        float2 w = twf[(a * mu) & 63];
        float v = p[a];
        re += v * w.x; im += v * w.y;
    }
    xf1[t] = make_float2(re, im);
}

__global__ void k_fh1(const float2* __restrict__ xf1, const float* __restrict__ dqtw,
                      const int* __restrict__ lm_l, float2* __restrict__ fh1) {
    int t = blockIdx.x * TPB + threadIdx.x;
    if (t >= kNM * kB * kF0) return;
    int lm = t / 6, rem = t % 6, z = rem / 3, f = rem % 3;
    int l = lm_l[lm], m = lm - l * l, R = 2 * l + 1, o3 = off3i(l);
    int mu = (m - l) & 63;
    const float4* wq = (const float4*)(dqtw + (size_t)o3 * 64 + (size_t)(m * R + l) * 64);
    const float2* xr = xf1 + (size_t)((z * 3 + f) * 64) * 64 + mu;
    float re0 = 0, im0 = 0, re1 = 0, im1 = 0;
    #pragma unroll
    for (int b4 = 0; b4 < 16; b4++) {
        float4 w4 = wq[b4];
        float2 v0 = xr[(4 * b4 + 0) * 64];
        float2 v1 = xr[(4 * b4 + 1) * 64];
        float2 v2 = xr[(4 * b4 + 2) * 64];
        float2 v3 = xr[(4 * b4 + 3) * 64];
        re0 += w4.x * v0.x + w4.y * v1.x; im0 += w4.x * v0.y + w4.y * v1.y;
        re1 += w4.z * v2.x + w4.w * v3.x; im1 += w4.z * v2.y + w4.w * v3.y;
    }
    const float C2 = 1.0f / 128.0f;
    fh1[t] = make_float2((re0 + re1) * C2, (im0 + im1) * C2);
}

// Layer-1 zs: o-tiled by 12, z-paired (same shape as k_zs; Fin = 3).
__global__ void k_zs1(const float2* __restrict__ fh1, const float2* __restrict__ khat,
                      const float* __restrict__ dehalf, const int* __restrict__ lmn_l,
                      float2* __restrict__ zs) {
    int nOg = kF1 / 12;                      // 5
    int t = blockIdx.x * TPB + threadIdx.x;  // og*NMN + lmn
    if (t >= nOg * kNMN) return;
    int lmn = t % kNMN, og = t / kNMN;
    int l = lmn_l[lmn], o3 = off3i(l), r = lmn - o3, R = 2 * l + 1;
    int m = r / R, n = r - m * R;
    int nu = (n - l) & 63;
    float de1 = dehalf[o3 + n * R + l];
    int o0 = og * 12;
    const float2* fp = fh1 + (size_t)(l * l + m) * 6;
    const float2* kp = khat + (size_t)o0 * 64 + nu;
    float2 c0[12], c1[12];
    #pragma unroll
    for (int i = 0; i < 12; i++) {
        c0[i] = make_float2(0.f, 0.f);
        c1[i] = make_float2(0.f, 0.f);
    }
    #pragma unroll
    for (int f = 0; f < kF0; f++) {
        float2 a0 = fp[f];       // z = 0
        float2 a1 = fp[3 + f];   // z = 1
        const float2* kf = kp + (size_t)f * kF1 * 64;
        #pragma unroll
        for (int i = 0; i < 12; i++) {
            float2 b = kf[(size_t)i * 64];   // conj applied below
            c0[i].x += a0.x * b.x + a0.y * b.y;
            c0[i].y += a0.y * b.x - a0.x * b.y;
            c1[i].x += a1.x * b.x + a1.y * b.y;
            c1[i].y += a1.y * b.x - a1.x * b.y;
        }
    }
    float2* zp0 = zs + (size_t)o0 * kNMN + lmn;
    float2* zp1 = zs + ((size_t)kF1 + o0) * kNMN + lmn;
    #pragma unroll
    for (int i = 0; i < 12; i++) {
        zp0[(size_t)i * kNMN] = make_float2(c0[i].x * de1, c0[i].y * de1);
        zp1[(size_t)i * kNMN] = make_float2(c1[i].x * de1, c1[i].y * de1);
    }
}

// 2D forward DFT (radix-8 x2) with fused BN+ReLU; float4 staging.
__global__ __launch_bounds__(TPB) void k_fft2(const float* __restrict__ y,
                                              float2* __restrict__ xf,
                                              const float2* __restrict__ twf_g,
                                              const float* __restrict__ stats,
                                              const float* __restrict__ gamma,
                                              const float* __restrict__ beta,
                                              int zf0) {
    __shared__ float sIn[64 * 65];
    __shared__ float2 sMid[64 * 66];
    __shared__ float2 tw[64];
    int blk = blockIdx.x, tid = threadIdx.x;
    if (tid < 64) tw[tid] = twf_g[tid];
    int o = (zf0 + (blk >> 6)) % kF1;
    const float inv = 1.0f / 524288.0f;
    float mean = stats[o * 2] * inv;
    float var = stats[o * 2 + 1] * inv - mean * mean;
    float rstd = rsqrtf(var + 1e-5f);
    float ga = gamma[o], be = beta[o];
    const float4* src4 = (const float4*)(y + (size_t)blk * 4096);
    for (int i = tid; i < 1024; i += TPB) {
        float4 v4 = src4[i];
        int row = i >> 4, col = (i & 15) << 2;
        float* d = sIn + row * 65 + col;
        float a0 = (v4.x - mean) * rstd * ga + be;
        float a1 = (v4.y - mean) * rstd * ga + be;
        float a2 = (v4.z - mean) * rstd * ga + be;
        float a3 = (v4.w - mean) * rstd * ga + be;
        d[0] = a0 > 0.f ? a0 : 0.f;
        d[1] = a1 > 0.f ? a1 : 0.f;
        d[2] = a2 > 0.f ? a2 : 0.f;
        d[3] = a3 > 0.f ? a3 : 0.f;
    }
    __syncthreads();
    float2 w8[8];
    #pragma unroll
    for (int k = 0; k < 8; k++) w8[k] = tw[k * 8];
    int r2 = tid >> 2, q = tid & 3;
    {   // dim-1: g -> nu, REAL input
        const float* rowp = sIn + r2 * 65;
        float2* mrow = sMid + r2 * 66;
        #pragma unroll
        for (int half = 0; half < 2; half++) {
            int s = q + 4 * half;
            float f[8];
            #pragma unroll
            for (int p = 0; p < 8; p++) f[p] = rowp[8 * p + s];
            float2 ws = tw[s];
            float2 t = make_float2(1.f, 0.f);
            #pragma unroll
            for (int v = 0; v < 8; v++) {
                float re = 0, im = 0;
                #pragma unroll
                for (int p = 0; p < 8; p++) {
                    float2 w = w8[(v * p) & 7];
                    re += f[p] * w.x; im += f[p] * w.y;
                }
                mrow[v * 8 + s] = make_float2(re * t.x - im * t.y, re * t.y + im * t.x);
                float tx = t.x * ws.x - t.y * ws.y;
                t.y = t.x * ws.y + t.y * ws.x; t.x = tx;
            }
        }
        float2 a[2][8];
        #pragma unroll
        for (int half = 0; half < 2; half++) {
            int v = q + 4 * half;
            #pragma unroll
            for (int s = 0; s < 8; s++) a[half][s] = mrow[v * 8 + s];
        }
        #pragma unroll
        for (int half = 0; half < 2; half++) {
            int v = q + 4 * half;
            #pragma unroll
            for (int u = 0; u < 8; u++) {
                float re = 0, im = 0;
                #pragma unroll
                for (int s = 0; s < 8; s++) {
                    float2 w = w8[(u * s) & 7];
                    re += a[half][s].x * w.x - a[half][s].y * w.y;
                    im += a[half][s].x * w.y + a[half][s].y * w.x;
                }
                mrow[8 * u + v] = make_float2(re, im);
            }
        }
    }
    __syncthreads();
    {   // dim-2: a -> mu per column c
        int c = r2;
        float2* dst = xf + (size_t)blk * 4096;
        #pragma unroll
        for (int half = 0; half < 2; half++) {
            int s = q + 4 * half;
            float2 f[8];
            #pragma unroll
            for (int p = 0; p < 8; p++) f[p] = sMid[(8 * p + s) * 66 + c];
            float2 ws = tw[s];
            float2 t = make_float2(1.f, 0.f);
            #pragma unroll
            for (int v = 0; v < 8; v++) {
                float re = 0, im = 0;
                #pragma unroll
                for (int p = 0; p < 8; p++) {
                    float2 w = w8[(v * p) & 7];
                    re += f[p].x * w.x - f[p].y * w.y;
                    im += f[p].x * w.y + f[p].y * w.x;
                }
                sMid[(v * 8 + s) * 66 + c] = make_float2(re * t.x - im * t.y,
                                                         re * t.y + im * t.x);
                float tx = t.x * ws.x - t.y * ws.y;
                t.y = t.x * ws.y + t.y * ws.x; t.x = tx;
            }
        }
        float2 a[2][8];
        #pragma unroll
        for (int half = 0; half < 2; half++) {
            int v = q + 4 * half;
            #pragma unroll
            for (int s = 0; s < 8; s++) a[half][s] = sMid[(v * 8 + s) * 66 + c];
        }
        #pragma unroll
        for (int half = 0; half < 2; half++) {
            int v = q + 4 * half;
            #pragma unroll
            for (int u = 0; u < 8; u++) {
                float re = 0, im = 0;
                #pragma unroll
                for (int s = 0; s < 8; s++) {
                    float2 w = w8[(u * s) & 7];
                    re += a[half][s].x * w.x - a[half][s].y * w.y;
                    im += a[half][s].x * w.y + a[half][s].y * w.x;
                }
                dst[(8 * u + v) * 64 + c] = make_float2(re, im);
            }
        }
    }
}

__global__ void k_fh3(const float2* __restrict__ xf, const float* __restrict__ dqtw,
                      const int* __restrict__ lmn_l, float2* __restrict__ fh_out, int nzf) {
    int t = blockIdx.x * TPB + threadIdx.x;
    if (t >= nzf * kNMN) return;
    int lmn = t % kNMN, zf = t / kNMN;
    int l = lmn_l[lmn], o3 = off3i(l), r = lmn - o3, R = 2 * l + 1;
    int m = r / R, n = r - m * R;
    int mu = (m - l) & 63, nu = (n - l) & 63;
    const float4* wq = (const float4*)(dqtw + (size_t)o3 * 64 + (size_t)r * 64);
    const float2* xp = xf + (size_t)zf * kCube + mu * 64 + nu;
    float re0 = 0, im0 = 0, re1 = 0, im1 = 0, re2 = 0, im2 = 0, re3 = 0, im3 = 0;
    #pragma unroll
    for (int b4 = 0; b4 < 16; b4++) {
        float4 w4 = wq[b4];
        float2 v0 = xp[(size_t)(4 * b4 + 0) * 4096];
        float2 v1 = xp[(size_t)(4 * b4 + 1) * 4096];
        float2 v2 = xp[(size_t)(4 * b4 + 2) * 4096];
        float2 v3 = xp[(size_t)(4 * b4 + 3) * 4096];
        re0 += w4.x * v0.x; im0 += w4.x * v0.y;
        re1 += w4.y * v1.x; im1 += w4.y * v1.y;
        re2 += w4.z * v2.x; im2 += w4.z * v2.y;
        re3 += w4.w * v3.x; im3 += w4.w * v3.y;
    }
    const float C3 = 1.0f / 8192.0f;
    fh_out[t] = make_float2((re0 + re1 + re2 + re3) * C3, (im0 + im1 + im2 + im3) * C3);
}

__global__ void k_G(const float2* __restrict__ fh, const float* __restrict__ deT,
                    const int* __restrict__ lmn_l, float2* __restrict__ G, int Fin) {
    int t = blockIdx.x * TPB + threadIdx.x;
    if (t >= kB * Fin * kNMN) return;
    int lmn = t % kNMN, zf = t / kNMN;
    int l = lmn_l[lmn], o3 = off3i(l), r = lmn - o3, R = 2 * l + 1;
    int m = r / R, n = r - m * R;
    const float2* fr = fh + (size_t)zf * kNMN + o3 + m * R;
    const float* dp = deT + o3 + n;
    float re0 = 0, im0 = 0, re1 = 0, im1 = 0;
    int k = 0;
    for (; k + 1 < R; k += 2) {
        float d0 = dp[k * R], d1 = dp[(k + 1) * R];
        float2 v0 = fr[k], v1 = fr[k + 1];
        re0 += d0 * v0.x; im0 += d0 * v0.y;
        re1 += d1 * v1.x; im1 += d1 * v1.y;
    }
    {
        float d0 = dp[k * R];
        float2 v0 = fr[k];
        re0 += d0 * v0.x; im0 += d0 * v0.y;
    }
    G[t] = make_float2(re0 + re1, im0 + im1);
}

// zs: o-tiled by 12, z-paired (14 loads : 96 FMA per f; G re-streamed 5x not 10x)
__global__ void k_zs(const float2* __restrict__ G, const float2* __restrict__ khat,
                     const int* __restrict__ lmn_l, float2* __restrict__ zs,
                     int Fin, int Fo) {
    int nOg = Fo / 12;                       // 5 (Fo=60), 3 (Fo=36)
    int t = blockIdx.x * TPB + threadIdx.x;
    if (t >= nOg * kNMN) return;
    int lmn = t % kNMN, og = t / kNMN;
    int l = lmn_l[lmn], r = lmn - off3i(l), R = 2 * l + 1;
    int n = r % R;
    int nu = (n - l) & 63;
    int o0 = og * 12;
    const float2* gp0 = G + lmn;
    const float2* gp1 = G + (size_t)Fin * kNMN + lmn;
    const float2* kp = khat + (size_t)o0 * 64 + nu;
    float2 c0[12], c1[12];
    #pragma unroll
    for (int i = 0; i < 12; i++) {
        c0[i] = make_float2(0.f, 0.f);
        c1[i] = make_float2(0.f, 0.f);
    }
    for (int f = 0; f < Fin; f++) {
        float2 a0 = gp0[(size_t)f * kNMN];
        float2 a1 = gp1[(size_t)f * kNMN];
        const float2* kf = kp + (size_t)f * Fo * 64;
        #pragma unroll
        for (int i = 0; i < 12; i++) {
            float2 b = kf[(size_t)i * 64];   // conj applied below
            c0[i].x += a0.x * b.x + a0.y * b.y;
            c0[i].y += a0.y * b.x - a0.x * b.y;
            c1[i].x += a1.x * b.x + a1.y * b.y;
            c1[i].y += a1.y * b.x - a1.x * b.y;
        }
    }
    float2* zp0 = zs + (size_t)o0 * kNMN + lmn;
    float2* zp1 = zs + ((size_t)Fo + o0) * kNMN + lmn;
    #pragma unroll
    for (int i = 0; i < 12; i++) {
        zp0[(size_t)i * kNMN] = c0[i];
        zp1[(size_t)i * kNMN] = c1[i];
    }
}

// Synthesis stage A: dense accumulation; LDS z reads via b128.
__global__ __launch_bounds__(TPB) void k_synA(const float2* __restrict__ zs,
                                              const float* __restrict__ dqz,
                                              float2* __restrict__ T) {
    __shared__ float2 sZ[2 * 32 * 64];
    int mu = blockIdx.x, p = blockIdx.y;
    int tid = threadIdx.x;
    int mt = (mu <= 31) ? mu : mu - 64;
    int am = mt < 0 ? -mt : mt;
    #pragma unroll
    for (int k = 0; k < 16; k++) {
        int i = tid + k * TPB;
        int nu = i & 63, l = (i >> 6) & 31, zo_i = i >> 11;
        int nt = (nu <= 31) ? nu : nu - 64;
        int an = nt < 0 ? -nt : nt;
        float2 v = make_float2(0.f, 0.f);
        if (l >= am && an <= l)
            v = zs[(size_t)(2 * p + zo_i) * kNMN + off3i(l) +
                   (mt + l) * (2 * l + 1) + nt + l];
        sZ[i] = v;
    }
    __syncthreads();
    int j = tid & 63, s = tid >> 6;
    float2 c0[16], c1[16];
    #pragma unroll
    for (int k = 0; k < 16; k++) {
        c0[k] = make_float2(0.f, 0.f);
        c1[k] = make_float2(0.f, 0.f);
    }
    for (int l = am; l < 32; l++) {
        const float* dp = dqz + ((size_t)(l * l + mt + l) * 64 + s * 16) * 64 + j;
        const float4* z04 = (const float4*)(sZ + (size_t)l * 64 + s * 16);
        const float4* z14 = (const float4*)(sZ + (size_t)(32 + l) * 64 + s * 16);
        #pragma unroll
        for (int h = 0; h < 8; h++) {
            float d0 = dp[(size_t)(2 * h) * 64];
            float d1 = dp[(size_t)(2 * h + 1) * 64];
            float4 za = z04[h];
            float4 zb = z14[h];
            c0[2 * h].x     += d0 * za.x; c0[2 * h].y     += d0 * za.y;
            c0[2 * h + 1].x += d1 * za.z; c0[2 * h + 1].y += d1 * za.w;
            c1[2 * h].x     += d0 * zb.x; c1[2 * h].y     += d0 * zb.y;
            c1[2 * h + 1].x += d1 * zb.z; c1[2 * h + 1].y += d1 * zb.w;
        }
    }
    float2* t0 = T + (((size_t)(2 * p + 0) * 64 + mu) * 64 + j) * 64 + s * 16;
    float2* t1 = T + (((size_t)(2 * p + 1) * 64 + mu) * 64 + j) * 64 + s * 16;
    #pragma unroll
    for (int k = 0; k < 16; k++) t0[k] = c0[k];
    #pragma unroll
    for (int k = 0; k < 16; k++) t1[k] = c1[k];
}

// Synthesis stage B: radix-8 x2 IDFT; float4 T staging; real + bias out.
__global__ __launch_bounds__(TPB) void k_synB(const float2* __restrict__ T,
                                              const float2* __restrict__ twi_g,
                                              const float* __restrict__ bias,
                                              float* __restrict__ yout,
                                              int Fo, int zo0) {
    __shared__ float2 sF[64 * 66];
    __shared__ float2 tw[64];
    int blk = blockIdx.x;
    int zo_l = blk >> 6, j = blk & 63;
    int zo_g = zo0 + zo_l;
    int o = zo_g % Fo;
    int tid = threadIdx.x;
    if (tid < 64) tw[tid] = twi_g[tid];
    const float4* src4 = (const float4*)(T + (size_t)zo_l * kCube + (size_t)j * 64);
    for (int i = tid; i < 2048; i += TPB) {
        int mu = i >> 5, half = i & 31;
        float4 v = src4[(size_t)mu * 2048 + half];
        sF[mu * 66 + 2 * half]     = make_float2(v.x, v.y);
        sF[mu * 66 + 2 * half + 1] = make_float2(v.z, v.w);
    }
    __syncthreads();
    float2 w8[8];
    #pragma unroll
    for (int k = 0; k < 8; k++) w8[k] = tw[k * 8];
    int r2 = tid >> 2, q = tid & 3;
    {   // dim-nu, complex in-place radix-8
        float2* mrow = sF + r2 * 66;
        #pragma unroll
        for (int half = 0; half < 2; half++) {
            int s = q + 4 * half;
            float2 f[8];
            #pragma unroll
            for (int p = 0; p < 8; p++) f[p] = mrow[8 * p + s];
            float2 ws = tw[s];
            float2 t = make_float2(1.f, 0.f);
            #pragma unroll
            for (int v = 0; v < 8; v++) {
                float re = 0, im = 0;
                #pragma unroll
                for (int p = 0; p < 8; p++) {
                    float2 w = w8[(v * p) & 7];
                    re += f[p].x * w.x - f[p].y * w.y;
                    im += f[p].x * w.y + f[p].y * w.x;
                }
                mrow[v * 8 + s] = make_float2(re * t.x - im * t.y, re * t.y + im * t.x);
                float tx = t.x * ws.x - t.y * ws.y;
                t.y = t.x * ws.y + t.y * ws.x; t.x = tx;
            }
        }
        float2 a[2][8];
        #pragma unroll
        for (int half = 0; half < 2; half++) {
            int v = q + 4 * half;
            #pragma unroll
            for (int s = 0; s < 8; s++) a[half][s] = mrow[v * 8 + s];
        }
        #pragma unroll
        for (int half = 0; half < 2; half++) {
            int v = q + 4 * half;
            #pragma unroll
            for (int u = 0; u < 8; u++) {
                float re = 0, im = 0;
                #pragma unroll
                for (int s = 0; s < 8; s++) {
                    float2 w = w8[(u * s) & 7];
                    re += a[half][s].x * w.x - a[half][s].y * w.y;
                    im += a[half][s].x * w.y + a[half][s].y * w.x;
                }
                mrow[8 * u + v] = make_float2(re, im);
            }
        }
    }
    __syncthreads();
    {   // dim-mu, per column c; real + bias out
        int c = r2;
        float bo = bias[o];
        float* dst = yout + ((size_t)zo_g * 64 + j) * 4096;
        #pragma unroll
        for (int half = 0; half < 2; half++) {
            int s = q + 4 * half;
            float2 f[8];
            #pragma unroll
            for (int p = 0; p < 8; p++) f[p] = sF[(8 * p + s) * 66 + c];
            float2 ws = tw[s];
            float2 t = make_float2(1.f, 0.f);
            #pragma unroll
            for (int v = 0; v < 8; v++) {
                float re = 0, im = 0;
                #pragma unroll
                for (int p = 0; p < 8; p++) {
                    float2 w = w8[(v * p) & 7];
                    re += f[p].x * w.x - f[p].y * w.y;
                    im += f[p].x * w.y + f[p].y * w.x;
                }
                sF[(v * 8 + s) * 66 + c] = make_float2(re * t.x - im * t.y,
                                                       re * t.y + im * t.x);
                float tx = t.x * ws.x - t.y * ws.y;
                t.y = t.x * ws.y + t.y * ws.x; t.x = tx;
            }
        }
        float2 a[2][8];
        #pragma unroll
        for (int half = 0; half < 2; half++) {
            int v = q + 4 * half;
            #pragma unroll
            for (int s = 0; s < 8; s++) a[half][s] = sF[(v * 8 + s) * 66 + c];
        }
        #pragma unroll
        for (int half = 0; half < 2; half++) {
            int v = q + 4 * half;
            #pragma unroll
            for (int u = 0; u < 8; u++) {
                float re = 0;
                #pragma unroll
                for (int s = 0; s < 8; s++) {
                    float2 w = w8[(u * s) & 7];
                    re += a[half][s].x * w.x - a[half][s].y * w.y;
                }
                dst[(8 * u + v) * 64 + c] = re + bo;
            }
        }
    }
}

__global__ void k_bn_stats(const float* __restrict__ y, float* __restrict__ stats, int Fo) {
    __shared__ float ss[TPB], sq[TPB];
    int o = blockIdx.y, chunk = blockIdx.x, tid = threadIdx.x;
    int base = chunk * 4096;
    int z = base >> 18, within = base & (kCube - 1);
    const float* p = y + ((size_t)(z * Fo + o) << 18) + within;
    float s = 0, q = 0;
    for (int k = 0; k < 16; k++) {
        float v = p[k * TPB + tid];
        s += v; q += v * v;
    }
    ss[tid] = s; sq[tid] = q;
    __syncthreads();
    for (int st = TPB / 2; st > 0; st >>= 1) {
        if (tid < st) { ss[tid] += ss[tid + st]; sq[tid] += sq[tid + st]; }
        __syncthreads();
    }
    if (tid == 0) {
        atomicAdd(&stats[o * 2], ss[0]);
        atomicAdd(&stats[o * 2 + 1], sq[0]);
    }
}

__global__ void k_final(const float* __restrict__ y, const float* __restrict__ stats,
                        const float* __restrict__ gamma, const float* __restrict__ beta,
                        float* __restrict__ out) {
    int t = blockIdx.x * TPB + threadIdx.x;
    if (t >= kB * kF2 * 4096) return;
    int zo = t >> 12, o = zo % kF2;
    const float inv = 1.0f / 524288.0f;
    float mean = stats[o * 2] * inv;
    float var = stats[o * 2 + 1] * inv - mean * mean;
    float rstd = rsqrtf(var + 1e-5f);
    float ga = gamma[o], be = beta[o];
    const float* p = y + (size_t)t * 64;
    float acc = 0;
    for (int g = 0; g < 64; g++) {
        float v = (p[g] - mean) * rstd * ga + be;
        acc += v > 0.f ? v : 0.f;
    }
    out[t] = acc * (1.0f / 64.0f);
}

// ---------------------------------------------------------------------------
extern "C" void kernel_launch(void* const* d_in, const int* in_sizes, int n_in,
                              void* d_out, int out_size, void* d_ws, size_t ws_size,
                              hipStream_t stream) {
    const float* x     = (const float*)d_in[0];
    const float* k1    = (const float*)d_in[1];
    const float* bias1 = (const float*)d_in[2];
    const float* g1    = (const float*)d_in[3];
    const float* be1   = (const float*)d_in[4];
    const float* k2    = (const float*)d_in[5];
    const float* bias2 = (const float*)d_in[6];
    const float* g2    = (const float*)d_in[7];
    const float* be2   = (const float*)d_in[8];
    const float* k3    = (const float*)d_in[9];
    const float* bias3 = (const float*)d_in[10];
    const float* g3    = (const float*)d_in[11];
    const float* be3   = (const float*)d_in[12];

    char* ws = (char*)d_ws;
    size_t off = 0;
    auto alloc = [&](size_t bytes) {
        size_t cur = off;
        off = (off + bytes + 255) & ~(size_t)255;
        return cur;
    };
    size_t o_const = alloc(g_tab.bytes);                       // 2.9 MB
    size_t o_dqz   = alloc((size_t)kNM * 64 * 64 * 4);         // 16.8 MB
    size_t o_dqtw  = alloc((size_t)64 * kNMN * 4);             // 11.2 MB
    size_t o_deT   = alloc((size_t)kNMN * 4);                  // 0.17 MB
    size_t o_khat  = alloc((size_t)kF1 * kF1 * 64 * 8);        // 1.8 MB
    size_t o_xf1   = alloc((size_t)kB * kF0 * 64 * 64 * 8);    // 0.2 MB
    size_t o_fh1   = alloc((size_t)kNM * kB * kF0 * 8);        // 0.05 MB
    size_t o_stats = alloc(2 * 64 * 4);
    size_t o_fh    = alloc((size_t)kB * kF1 * kNMN * 8);       // 42 MB (fh, then zs)
    size_t o_scr   = alloc((size_t)kFCH * kCube * 8);          // 50.3 MB (dtmp/xf/G/T)
    size_t o_cube  = alloc((size_t)kB * kF1 * kCube * 4);      // 126 MB
    if (off > ws_size) return;

    const float* cb = (const float*)(ws + o_const);
    const float2* twf = (const float2*)(cb + g_tab.o_twf);
    const float2* twi = (const float2*)(cb + g_tab.o_twi);
    const float* w_t = cb + g_tab.o_w;
    const float* etab = cb + g_tab.o_etab;
    const float* dehalf = etab + (size_t)(8 + 4) * kNMN;  // G_4 = E0^32 = d(pi/2)
    const int* lmn_l = (const int*)(cb + g_tab.o_lmnl);
    const int* lm_l = (const int*)(cb + g_tab.o_lml);

    float* dqz = (float*)(ws + o_dqz);
    float* dqtw = (float*)(ws + o_dqtw);
    float* deT = (float*)(ws + o_deT);
    float2* khat = (float2*)(ws + o_khat);
    float2* xf1 = (float2*)(ws + o_xf1);
    float2* fh1 = (float2*)(ws + o_fh1);
    float* stats = (float*)(ws + o_stats);
    float2* fh = (float2*)(ws + o_fh);
    float2* zsb = (float2*)(ws + o_fh);
    float* dtmp = (float*)(ws + o_scr);
    float2* Gb = (float2*)(ws + o_scr);
    float2* xfc = (float2*)(ws + o_scr);
    float2* Tb = (float2*)(ws + o_scr);
    float* cube = (float*)(ws + o_cube);

    hipMemcpyAsync(ws + o_const, g_tab.blob.data(), g_tab.bytes,
                   hipMemcpyHostToDevice, stream);
    hipMemsetAsync(dqz, 0, (size_t)kNM * 64 * 64 * 4, stream);
    k_gendqA<<<kLMAX * 64, TPB, 0, stream>>>(etab, dtmp);
    k_scat<<<kLMAX * 63, TPB, 0, stream>>>(dtmp, w_t, dqz, dqtw);
    k_transde<<<(kNMN + TPB - 1) / TPB, TPB, 0, stream>>>(dehalf, deT, lmn_l);

    const float S2S = 1.0f / sqrtf(64.0f * 3.0f * 1024.0f);
    const float SO3S = 1.0f / sqrtf(64.0f * 60.0f);
    auto blks = [](size_t n) { return (int)((n + TPB - 1) / TPB); };

    auto synth = [&](const float* bi, int Fo) {
        int planes = kB * Fo;
        for (int zo0 = 0; zo0 < planes; zo0 += kFCH) {
            int nzo = planes - zo0 < kFCH ? planes - zo0 : kFCH;
            k_synA<<<dim3(64, nzo / 2), TPB, 0, stream>>>(
                zsb + (size_t)zo0 * kNMN, dqz, Tb);
            k_synB<<<nzo * 64, TPB, 0, stream>>>(Tb, twi, bi, cube, Fo, zo0);
        }
    };
    auto bnstats = [&](int Fo) {
        hipMemsetAsync(stats, 0, 2 * 64 * 4, stream);
        k_bn_stats<<<dim3(128, Fo), TPB, 0, stream>>>(cube, stats, Fo);
    };

    // ---- Layer 1: S2 conv -> cube ----
    k_khat<<<blks(kF0 * kF1 * 64), TPB, 0, stream>>>(k1, khat, twf, kF0 * kF1 * 64, S2S);
    k_fft1<<<blks(kB * kF0 * 64 * 64), TPB, 0, stream>>>(x, xf1, twf);
    k_fh1<<<blks(kNM * kB * kF0), TPB, 0, stream>>>(xf1, dqtw, lm_l, fh1);
    k_zs1<<<blks((size_t)(kF1 / 12) * kNMN), TPB, 0, stream>>>(fh1, khat, dehalf, lmn_l, zsb);
    synth(bias1, kF1);
    bnstats(kF1);

    // ---- Layers 2 & 3: SO3 conv; fft2 applies previous layer's BN+ReLU ----
    for (int layer = 2; layer <= 3; layer++) {
        int Fo = (layer == 2) ? kF1 : kF2;
        const float* kk = (layer == 2) ? k2 : k3;
        const float* bi = (layer == 2) ? bias2 : bias3;
        const float* gp = (layer == 2) ? g1 : g2;
        const float* bp = (layer == 2) ? be1 : be2;
        k_khat<<<blks(kF1 * Fo * 64), TPB, 0, stream>>>(kk, khat, twf, kF1 * Fo * 64, SO3S);
        for (int zf0 = 0; zf0 < kB * kF1; zf0 += kFCH) {
            int nzf = kB * kF1 - zf0 < kFCH ? kB * kF1 - zf0 : kFCH;
            k_fft2<<<nzf * 64, TPB, 0, stream>>>(cube + (size_t)zf0 * kCube, xfc,
                                                 twf, stats, gp, bp, zf0);
            k_fh3<<<blks((size_t)nzf * kNMN), TPB, 0, stream>>>(
                xfc, dqtw, lmn_l, fh + (size_t)zf0 * kNMN, nzf);
        }
        k_G<<<blks((size_t)kB * kF1 * kNMN), TPB, 0, stream>>>(fh, deT, lmn_l, Gb, kF1);
        k_zs<<<blks((size_t)(Fo / 12) * kNMN), TPB, 0, stream>>>(Gb, khat, lmn_l, zsb, kF1, Fo);
        synth(bi, Fo);
        bnstats(Fo);
        if (layer == 3)
            k_final<<<blks(kB * kF2 * 4096), TPB, 0, stream>>>(cube, stats, g3, be3, (float*)d_out);
    }
}

// Round 15
// 3299.133 us; speedup vs baseline: 1.1367x; 1.1367x over previous
//
#include <hip/hip_runtime.h>
#include <cmath>
#include <cstring>
#include <cstdint>
#include <vector>

#define TPB 256
static constexpr int kLMAX = 32;
static constexpr int kNMN  = 43680;   // sum_{l<32} (2l+1)^2
static constexpr int kNM   = 1024;    // sum_{l<32} (2l+1)
static constexpr int kB    = 2;
static constexpr int kF0   = 3, kF1 = 60, kF2 = 36;
static constexpr int kCube = 262144;  // 64^3
static constexpr int kFCH  = 24;      // plane chunk (divides 120 and 72)

__host__ __device__ inline int off3i(int l) { return l * (4 * l * l - 1) / 3; }

// ---------------------------------------------------------------------------
// Host-side constant tables (~2.9 MB seeds; d_b = F_{b&7} * G_{b>>3}).
// ---------------------------------------------------------------------------
static void h_matmul(const std::vector<double>& A, const std::vector<double>& B,
                     std::vector<double>& C, int n) {
    C.assign((size_t)n * n, 0.0);
    for (int i = 0; i < n; i++)
        for (int k = 0; k < n; k++) {
            double a = A[(size_t)i * n + k];
            if (a == 0.0) continue;
            const double* bp = &B[(size_t)k * n];
            double* cp = &C[(size_t)i * n];
            for (int j = 0; j < n; j++) cp[j] += a * bp[j];
        }
}

struct HostTables {
    std::vector<float> blob;
    size_t o_twf, o_twi, o_w, o_lmnl, o_lml, o_etab;
    size_t bytes;
    HostTables() {
        size_t n = 0;
        o_twf = n;  n += 128;
        o_twi = n;  n += 128;
        o_w = n;    n += 64;
        o_lmnl = n; n += kNMN;
        o_lml = n;  n += kNM;
        o_etab = n; n += (size_t)16 * kNMN;    // [F_0..F_7, G_0..G_7] per l
        blob.assign(n, 0.0f);
        bytes = n * 4;

        for (int k = 0; k < 64; k++) {
            double th = -2.0 * M_PI * k / 64.0;
            blob[o_twf + 2 * k]     = (float)cos(th);
            blob[o_twf + 2 * k + 1] = (float)sin(th);
            blob[o_twi + 2 * k]     = (float)cos(th);
            blob[o_twi + 2 * k + 1] = (float)(-sin(th));
        }
        for (int j = 0; j < 64; j++) {
            double s = 0;
            for (int k = 0; k < 32; k++)
                s += sin((2.0 * j + 1) * (2.0 * k + 1) * M_PI / 128.0) / (2.0 * k + 1);
            blob[o_w + j] = (float)(2.0 / 32.0 * sin(M_PI * (2.0 * j + 1) / 128.0) * s);
        }
        std::vector<double> A, Eh, E0, E08, F, G, term, tmp;
        for (int l = 0; l < kLMAX; l++) {
            int R = 2 * l + 1, o3 = off3i(l);
            A.assign((size_t)R * R, 0.0);
            for (int i = 0; i + 1 < R; i++) {
                double m = (double)i - l;
                double c = sqrt((double)l * (l + 1) - m * (m + 1));
                A[(size_t)(i + 1) * R + i] = -(M_PI / 128.0) * c * 0.5;
                A[(size_t)i * R + (i + 1)] =  (M_PI / 128.0) * c * 0.5;
            }
            Eh.assign((size_t)R * R, 0.0);
            for (int i = 0; i < R; i++) Eh[(size_t)i * R + i] = 1.0;
            term = Eh;
            for (int k = 1; k <= 30; k++) {
                h_matmul(term, A, tmp, R);
                for (auto& v : tmp) v /= k;
                term = tmp;
                for (size_t i = 0; i < (size_t)R * R; i++) Eh[i] += term[i];
            }
            h_matmul(Eh, Eh, E0, R);
            h_matmul(E0, E0, tmp, R);
            h_matmul(tmp, tmp, E08, R);
            h_matmul(E08, E08, tmp, R); E08 = tmp;  // E0^8
            F = Eh;
            for (int lo = 0; lo < 8; lo++) {
                for (int r = 0; r < R * R; r++)
                    blob[o_etab + (size_t)lo * kNMN + o3 + r] = (float)F[r];
                if (lo < 7) { h_matmul(F, E0, tmp, R); F = tmp; }
            }
            G.assign((size_t)R * R, 0.0);
            for (int i = 0; i < R; i++) G[(size_t)i * R + i] = 1.0;
            for (int hi = 0; hi < 8; hi++) {
                for (int r = 0; r < R * R; r++)
                    blob[o_etab + (size_t)(8 + hi) * kNMN + o3 + r] = (float)G[r];
                if (hi < 7) { h_matmul(G, E08, tmp, R); G = tmp; }
            }
            int32_t li = l;
            for (int r = 0; r < R * R; r++) memcpy(&blob[o_lmnl + o3 + r], &li, 4);
            for (int m = 0; m < R; m++)    memcpy(&blob[o_lml + (size_t)l * l + m], &li, 4);
        }
    }
};
static HostTables g_tab;

// ---------------------------------------------------------------------------
__global__ __launch_bounds__(TPB) void k_gendqA(const float* __restrict__ etab,
                                                float* __restrict__ dtmp) {
    __shared__ float Fm[3969];
    __shared__ float Gm[63 * 64];
    int l = blockIdx.x >> 6, b = blockIdx.x & 63;
    int lo = b & 7, hi = b >> 3;
    int R = 2 * l + 1, RR = R * R, o3 = off3i(l);
    int tid = threadIdx.x;
    const float* Fsrc = etab + (size_t)lo * kNMN + o3;
    const float* Gsrc = etab + (size_t)(8 + hi) * kNMN + o3;
    for (int i = tid; i < RR; i += TPB) Fm[i] = Fsrc[i];
    for (int i = tid; i < R * 64; i += TPB) {
        int k = i >> 6, c = i & 63;
        Gm[i] = (c < R) ? Gsrc[k * R + c] : 0.f;
    }
    __syncthreads();
    int Gc = (R + 15) >> 4;
    if (tid < R * Gc) {
        int row = tid / Gc, g = tid - row * Gc;
        float4 A0 = make_float4(0,0,0,0), A1 = A0, A2 = A0, A3 = A0;
        const float* fr = Fm + row * R;
        for (int k = 0; k < R; k++) {
            float a = fr[k];
            const float4* gp = (const float4*)(Gm + (k << 6) + (g << 4));
            float4 q0 = gp[0], q1 = gp[1], q2 = gp[2], q3 = gp[3];
            A0.x += a * q0.x; A0.y += a * q0.y; A0.z += a * q0.z; A0.w += a * q0.w;
            A1.x += a * q1.x; A1.y += a * q1.y; A1.z += a * q1.z; A1.w += a * q1.w;
            A2.x += a * q2.x; A2.y += a * q2.y; A2.z += a * q2.z; A2.w += a * q2.w;
            A3.x += a * q3.x; A3.y += a * q3.y; A3.z += a * q3.z; A3.w += a * q3.w;
        }
        float v[16] = {A0.x,A0.y,A0.z,A0.w, A1.x,A1.y,A1.z,A1.w,
                       A2.x,A2.y,A2.z,A2.w, A3.x,A3.y,A3.z,A3.w};
        float* dst = dtmp + (size_t)o3 * 64 + (size_t)b * RR + row * R;
        int c0 = g << 4;
        #pragma unroll
        for (int e = 0; e < 16; e++)
            if (c0 + e < R) dst[c0 + e] = v[e];
    }
}

__global__ __launch_bounds__(TPB) void k_scat(const float* __restrict__ dtmp,
                                              const float* __restrict__ w,
                                              float* __restrict__ dqz,
                                              float* __restrict__ dqtw) {
    __shared__ float S[64 * 65];
    int l = blockIdx.x / 63, tile = blockIdx.x % 63;
    int R = 2 * l + 1, RR = R * R, o3 = off3i(l);
    int i0 = tile * 64;
    if (i0 >= RR) return;
    int tid = threadIdx.x;
    const float* src = dtmp + (size_t)o3 * 64;
    #pragma unroll
    for (int s = 0; s < 16; s++) {
        int idx = tid + s * TPB;
        int b = idx >> 6, ii = idx & 63;
        int i = i0 + ii;
        S[ii * 65 + b] = (i < RR) ? src[(size_t)b * RR + i] : 0.f;
    }
    __syncthreads();
    float Rf = (float)R;
    #pragma unroll
    for (int s = 0; s < 16; s++) {
        int idx = tid + s * TPB;
        int ii = idx >> 6, b = idx & 63;
        int i = i0 + ii;
        if (i < RR) {
            float v = S[ii * 65 + b];
            dqtw[((size_t)o3 + i) * 64 + b] = w[b] * v;
            int mi = i / R, ni = i - mi * R;
            int nu = (ni - l) & 63;
            dqz[((size_t)(l * l + mi) * 64 + nu) * 64 + b] = Rf * v;
        }
    }
}

__global__ void k_transde(const float* __restrict__ dehalf, float* __restrict__ deT,
                          const int* __restrict__ lmn_l) {
    int t = blockIdx.x * TPB + threadIdx.x;
    if (t >= kNMN) return;
    int l = lmn_l[t], o3 = off3i(l), r = t - o3, R = 2 * l + 1;
    int n = r / R, k = r - n * R;
    deT[o3 + k * R + n] = dehalf[t];
}

__global__ void k_khat(const float* __restrict__ kern, float2* __restrict__ khat,
                       const float2* __restrict__ twf, int total, float scale) {
    int t = blockIdx.x * TPB + threadIdx.x;
    if (t >= total) return;
    int nu = t & 63, fo = t >> 6;
    const float* row = kern + (size_t)fo * 64;
    float re = 0, im = 0;
    for (int p = 0; p < 64; p++) {
        float2 w = twf[(p * nu) & 63];
        float v = row[p];
        re += v * w.x; im += v * w.y;
    }
    khat[t] = make_float2(re * scale, im * scale);
}

__global__ void k_fft1(const float* __restrict__ x, float2* __restrict__ xf1,
                       const float2* __restrict__ twf) {
    int t = blockIdx.x * TPB + threadIdx.x;
    if (t >= kB * kF0 * 64 * 64) return;
    int mu = t & 63, row = t >> 6;
    const float* p = x + (size_t)row * 64;
    float re = 0, im = 0;
    for (int a = 0; a < 64; a++) {
        float2 w = twf[(a * mu) & 63];
        float v = p[a];
        re += v * w.x; im += v * w.y;
    }
    xf1[t] = make_float2(re, im);
}

__global__ void k_fh1(const float2* __restrict__ xf1, const float* __restrict__ dqtw,
                      const int* __restrict__ lm_l, float2* __restrict__ fh1) {
    int t = blockIdx.x * TPB + threadIdx.x;
    if (t >= kNM * kB * kF0) return;
    int lm = t / 6, rem = t % 6, z = rem / 3, f = rem % 3;
    int l = lm_l[lm], m = lm - l * l, R = 2 * l + 1, o3 = off3i(l);
    int mu = (m - l) & 63;
    const float4* wq = (const float4*)(dqtw + (size_t)o3 * 64 + (size_t)(m * R + l) * 64);
    const float2* xr = xf1 + (size_t)((z * 3 + f) * 64) * 64 + mu;
    float re0 = 0, im0 = 0, re1 = 0, im1 = 0;
    #pragma unroll
    for (int b4 = 0; b4 < 16; b4++) {
        float4 w4 = wq[b4];
        float2 v0 = xr[(4 * b4 + 0) * 64];
        float2 v1 = xr[(4 * b4 + 1) * 64];
        float2 v2 = xr[(4 * b4 + 2) * 64];
        float2 v3 = xr[(4 * b4 + 3) * 64];
        re0 += w4.x * v0.x + w4.y * v1.x; im0 += w4.x * v0.y + w4.y * v1.y;
        re1 += w4.z * v2.x + w4.w * v3.x; im1 += w4.z * v2.y + w4.w * v3.y;
    }
    const float C2 = 1.0f / 128.0f;
    fh1[t] = make_float2((re0 + re1) * C2, (im0 + im1) * C2);
}

// Layer-1 zs: o-tiled by 6, z-paired (same register shape as proven k_zs).
__global__ void k_zs1(const float2* __restrict__ fh1, const float2* __restrict__ khat,
                      const float* __restrict__ dehalf, const int* __restrict__ lmn_l,
                      float2* __restrict__ zs) {
    int nOg = kF1 / 6;                       // 10
    int t = blockIdx.x * TPB + threadIdx.x;  // og*NMN + lmn
    if (t >= nOg * kNMN) return;
    int lmn = t % kNMN, og = t / kNMN;
    int l = lmn_l[lmn], o3 = off3i(l), r = lmn - o3, R = 2 * l + 1;
    int m = r / R, n = r - m * R;
    int nu = (n - l) & 63;
    float de1 = dehalf[o3 + n * R + l];
    int o0 = og * 6;
    const float2* fp = fh1 + (size_t)(l * l + m) * 6;
    const float2* kp = khat + (size_t)o0 * 64 + nu;
    float2 c0[6], c1[6];
    #pragma unroll
    for (int i = 0; i < 6; i++) {
        c0[i] = make_float2(0.f, 0.f);
        c1[i] = make_float2(0.f, 0.f);
    }
    #pragma unroll
    for (int f = 0; f < kF0; f++) {
        float2 a0 = fp[f];       // z = 0
        float2 a1 = fp[3 + f];   // z = 1
        const float2* kf = kp + (size_t)f * kF1 * 64;
        #pragma unroll
        for (int i = 0; i < 6; i++) {
            float2 b = kf[(size_t)i * 64];   // conj applied below
            c0[i].x += a0.x * b.x + a0.y * b.y;
            c0[i].y += a0.y * b.x - a0.x * b.y;
            c1[i].x += a1.x * b.x + a1.y * b.y;
            c1[i].y += a1.y * b.x - a1.x * b.y;
        }
    }
    float2* zp0 = zs + (size_t)o0 * kNMN + lmn;
    float2* zp1 = zs + ((size_t)kF1 + o0) * kNMN + lmn;
    #pragma unroll
    for (int i = 0; i < 6; i++) {
        zp0[(size_t)i * kNMN] = make_float2(c0[i].x * de1, c0[i].y * de1);
        zp1[(size_t)i * kNMN] = make_float2(c1[i].x * de1, c1[i].y * de1);
    }
}

// 2D forward DFT (radix-8 x2) with fused BN+ReLU; float4 staging.
__global__ __launch_bounds__(TPB) void k_fft2(const float* __restrict__ y,
                                              float2* __restrict__ xf,
                                              const float2* __restrict__ twf_g,
                                              const float* __restrict__ stats,
                                              const float* __restrict__ gamma,
                                              const float* __restrict__ beta,
                                              int zf0) {
    __shared__ float sIn[64 * 65];
    __shared__ float2 sMid[64 * 66];
    __shared__ float2 tw[64];
    int blk = blockIdx.x, tid = threadIdx.x;
    if (tid < 64) tw[tid] = twf_g[tid];
    int o = (zf0 + (blk >> 6)) % kF1;
    const float inv = 1.0f / 524288.0f;
    float mean = stats[o * 2] * inv;
    float var = stats[o * 2 + 1] * inv - mean * mean;
    float rstd = rsqrtf(var + 1e-5f);
    float ga = gamma[o], be = beta[o];
    const float4* src4 = (const float4*)(y + (size_t)blk * 4096);
    for (int i = tid; i < 1024; i += TPB) {
        float4 v4 = src4[i];
        int row = i >> 4, col = (i & 15) << 2;
        float* d = sIn + row * 65 + col;
        float a0 = (v4.x - mean) * rstd * ga + be;
        float a1 = (v4.y - mean) * rstd * ga + be;
        float a2 = (v4.z - mean) * rstd * ga + be;
        float a3 = (v4.w - mean) * rstd * ga + be;
        d[0] = a0 > 0.f ? a0 : 0.f;
        d[1] = a1 > 0.f ? a1 : 0.f;
        d[2] = a2 > 0.f ? a2 : 0.f;
        d[3] = a3 > 0.f ? a3 : 0.f;
    }
    __syncthreads();
    float2 w8[8];
    #pragma unroll
    for (int k = 0; k < 8; k++) w8[k] = tw[k * 8];
    int r2 = tid >> 2, q = tid & 3;
    {   // dim-1: g -> nu, REAL input
        const float* rowp = sIn + r2 * 65;
        float2* mrow = sMid + r2 * 66;
        #pragma unroll
        for (int half = 0; half < 2; half++) {
            int s = q + 4 * half;
            float f[8];
            #pragma unroll
            for (int p = 0; p < 8; p++) f[p] = rowp[8 * p + s];
            float2 ws = tw[s];
            float2 t = make_float2(1.f, 0.f);
            #pragma unroll
            for (int v = 0; v < 8; v++) {
                float re = 0, im = 0;
                #pragma unroll
                for (int p = 0; p < 8; p++) {
                    float2 w = w8[(v * p) & 7];
                    re += f[p] * w.x; im += f[p] * w.y;
                }
                mrow[v * 8 + s] = make_float2(re * t.x - im * t.y, re * t.y + im * t.x);
                float tx = t.x * ws.x - t.y * ws.y;
                t.y = t.x * ws.y + t.y * ws.x; t.x = tx;
            }
        }
        float2 a[2][8];
        #pragma unroll
        for (int half = 0; half < 2; half++) {
            int v = q + 4 * half;
            #pragma unroll
            for (int s = 0; s < 8; s++) a[half][s] = mrow[v * 8 + s];
        }
        #pragma unroll
        for (int half = 0; half < 2; half++) {
            int v = q + 4 * half;
            #pragma unroll
            for (int u = 0; u < 8; u++) {
                float re = 0, im = 0;
                #pragma unroll
                for (int s = 0; s < 8; s++) {
                    float2 w = w8[(u * s) & 7];
                    re += a[half][s].x * w.x - a[half][s].y * w.y;
                    im += a[half][s].x * w.y + a[half][s].y * w.x;
                }
                mrow[8 * u + v] = make_float2(re, im);
            }
        }
    }
    __syncthreads();
    {   // dim-2: a -> mu per column c
        int c = r2;
        float2* dst = xf + (size_t)blk * 4096;
        #pragma unroll
        for (int half = 0; half < 2; half++) {
            int s = q + 4 * half;
            float2 f[8];
            #pragma unroll
            for (int p = 0; p < 8; p++) f[p] = sMid[(8 * p + s) * 66 + c];
            float2 ws = tw[s];
            float2 t = make_float2(1.f, 0.f);
            #pragma unroll
            for (int v = 0; v < 8; v++) {
                float re = 0, im = 0;
                #pragma unroll
                for (int p = 0; p < 8; p++) {
                    float2 w = w8[(v * p) & 7];
                    re += f[p].x * w.x - f[p].y * w.y;
                    im += f[p].x * w.y + f[p].y * w.x;
                }
                sMid[(v * 8 + s) * 66 + c] = make_float2(re * t.x - im * t.y,
                                                         re * t.y + im * t.x);
                float tx = t.x * ws.x - t.y * ws.y;
                t.y = t.x * ws.y + t.y * ws.x; t.x = tx;
            }
        }
        float2 a[2][8];
        #pragma unroll
        for (int half = 0; half < 2; half++) {
            int v = q + 4 * half;
            #pragma unroll
            for (int s = 0; s < 8; s++) a[half][s] = sMid[(v * 8 + s) * 66 + c];
        }
        #pragma unroll
        for (int half = 0; half < 2; half++) {
            int v = q + 4 * half;
            #pragma unroll
            for (int u = 0; u < 8; u++) {
                float re = 0, im = 0;
                #pragma unroll
                for (int s = 0; s < 8; s++) {
                    float2 w = w8[(u * s) & 7];
                    re += a[half][s].x * w.x - a[half][s].y * w.y;
                    im += a[half][s].x * w.y + a[half][s].y * w.x;
                }
                dst[(8 * u + v) * 64 + c] = make_float2(re, im);
            }
        }
    }
}

__global__ void k_fh3(const float2* __restrict__ xf, const float* __restrict__ dqtw,
                      const int* __restrict__ lmn_l, float2* __restrict__ fh_out, int nzf) {
    int t = blockIdx.x * TPB + threadIdx.x;
    if (t >= nzf * kNMN) return;
    int lmn = t % kNMN, zf = t / kNMN;
    int l = lmn_l[lmn], o3 = off3i(l), r = lmn - o3, R = 2 * l + 1;
    int m = r / R, n = r - m * R;
    int mu = (m - l) & 63, nu = (n - l) & 63;
    const float4* wq = (const float4*)(dqtw + (size_t)o3 * 64 + (size_t)r * 64);
    const float2* xp = xf + (size_t)zf * kCube + mu * 64 + nu;
    float re0 = 0, im0 = 0, re1 = 0, im1 = 0, re2 = 0, im2 = 0, re3 = 0, im3 = 0;
    #pragma unroll
    for (int b4 = 0; b4 < 16; b4++) {
        float4 w4 = wq[b4];
        float2 v0 = xp[(size_t)(4 * b4 + 0) * 4096];
        float2 v1 = xp[(size_t)(4 * b4 + 1) * 4096];
        float2 v2 = xp[(size_t)(4 * b4 + 2) * 4096];
        float2 v3 = xp[(size_t)(4 * b4 + 3) * 4096];
        re0 += w4.x * v0.x; im0 += w4.x * v0.y;
        re1 += w4.y * v1.x; im1 += w4.y * v1.y;
        re2 += w4.z * v2.x; im2 += w4.z * v2.y;
        re3 += w4.w * v3.x; im3 += w4.w * v3.y;
    }
    const float C3 = 1.0f / 8192.0f;
    fh_out[t] = make_float2((re0 + re1 + re2 + re3) * C3, (im0 + im1 + im2 + im3) * C3);
}

__global__ void k_G(const float2* __restrict__ fh, const float* __restrict__ deT,
                    const int* __restrict__ lmn_l, float2* __restrict__ G, int Fin) {
    int t = blockIdx.x * TPB + threadIdx.x;
    if (t >= kB * Fin * kNMN) return;
    int lmn = t % kNMN, zf = t / kNMN;
    int l = lmn_l[lmn], o3 = off3i(l), r = lmn - o3, R = 2 * l + 1;
    int m = r / R, n = r - m * R;
    const float2* fr = fh + (size_t)zf * kNMN + o3 + m * R;
    const float* dp = deT + o3 + n;
    float re0 = 0, im0 = 0, re1 = 0, im1 = 0;
    int k = 0;
    for (; k + 1 < R; k += 2) {
        float d0 = dp[k * R], d1 = dp[(k + 1) * R];
        float2 v0 = fr[k], v1 = fr[k + 1];
        re0 += d0 * v0.x; im0 += d0 * v0.y;
        re1 += d1 * v1.x; im1 += d1 * v1.y;
    }
    {
        float d0 = dp[k * R];
        float2 v0 = fr[k];
        re0 += d0 * v0.x; im0 += d0 * v0.y;
    }
    G[t] = make_float2(re0 + re1, im0 + im1);
}

// zs: o-tile 6, z-paired (proven no-spill shape; all loads wave-coalesced)
__global__ void k_zs(const float2* __restrict__ G, const float2* __restrict__ khat,
                     const int* __restrict__ lmn_l, float2* __restrict__ zs,
                     int Fin, int Fo) {
    int nOg = Fo / 6;
    int t = blockIdx.x * TPB + threadIdx.x;
    if (t >= nOg * kNMN) return;
    int lmn = t % kNMN, og = t / kNMN;
    int l = lmn_l[lmn], r = lmn - off3i(l), R = 2 * l + 1;
    int n = r % R;
    int nu = (n - l) & 63;
    int o0 = og * 6;
    const float2* gp0 = G + lmn;
    const float2* gp1 = G + (size_t)Fin * kNMN + lmn;
    const float2* kp = khat + (size_t)o0 * 64 + nu;
    float2 c0[6], c1[6];
    #pragma unroll
    for (int i = 0; i < 6; i++) {
        c0[i] = make_float2(0.f, 0.f);
        c1[i] = make_float2(0.f, 0.f);
    }
    for (int f = 0; f < Fin; f++) {
        float2 a0 = gp0[(size_t)f * kNMN];
        float2 a1 = gp1[(size_t)f * kNMN];
        const float2* kf = kp + (size_t)f * Fo * 64;
        #pragma unroll
        for (int i = 0; i < 6; i++) {
            float2 b = kf[(size_t)i * 64];
            c0[i].x += a0.x * b.x + a0.y * b.y;
            c0[i].y += a0.y * b.x - a0.x * b.y;
            c1[i].x += a1.x * b.x + a1.y * b.y;
            c1[i].y += a1.y * b.x - a1.x * b.y;
        }
    }
    float2* zp0 = zs + (size_t)o0 * kNMN + lmn;
    float2* zp1 = zs + ((size_t)Fo + o0) * kNMN + lmn;
    #pragma unroll
    for (int i = 0; i < 6; i++) {
        zp0[(size_t)i * kNMN] = c0[i];
        zp1[(size_t)i * kNMN] = c1[i];
    }
}

// Synthesis stage A: dense accumulation; LDS z reads via b128.
__global__ __launch_bounds__(TPB) void k_synA(const float2* __restrict__ zs,
                                              const float* __restrict__ dqz,
                                              float2* __restrict__ T) {
    __shared__ float2 sZ[2 * 32 * 64];
    int mu = blockIdx.x, p = blockIdx.y;
    int tid = threadIdx.x;
    int mt = (mu <= 31) ? mu : mu - 64;
    int am = mt < 0 ? -mt : mt;
    #pragma unroll
    for (int k = 0; k < 16; k++) {
        int i = tid + k * TPB;
        int nu = i & 63, l = (i >> 6) & 31, zo_i = i >> 11;
        int nt = (nu <= 31) ? nu : nu - 64;
        int an = nt < 0 ? -nt : nt;
        float2 v = make_float2(0.f, 0.f);
        if (l >= am && an <= l)
            v = zs[(size_t)(2 * p + zo_i) * kNMN + off3i(l) +
                   (mt + l) * (2 * l + 1) + nt + l];
        sZ[i] = v;
    }
    __syncthreads();
    int j = tid & 63, s = tid >> 6;
    float2 c0[16], c1[16];
    #pragma unroll
    for (int k = 0; k < 16; k++) {
        c0[k] = make_float2(0.f, 0.f);
        c1[k] = make_float2(0.f, 0.f);
    }
    for (int l = am; l < 32; l++) {
        const float* dp = dqz + ((size_t)(l * l + mt + l) * 64 + s * 16) * 64 + j;
        const float4* z04 = (const float4*)(sZ + (size_t)l * 64 + s * 16);
        const float4* z14 = (const float4*)(sZ + (size_t)(32 + l) * 64 + s * 16);
        #pragma unroll
        for (int h = 0; h < 8; h++) {
            float d0 = dp[(size_t)(2 * h) * 64];
            float d1 = dp[(size_t)(2 * h + 1) * 64];
            float4 za = z04[h];
            float4 zb = z14[h];
            c0[2 * h].x     += d0 * za.x; c0[2 * h].y     += d0 * za.y;
            c0[2 * h + 1].x += d1 * za.z; c0[2 * h + 1].y += d1 * za.w;
            c1[2 * h].x     += d0 * zb.x; c1[2 * h].y     += d0 * zb.y;
            c1[2 * h + 1].x += d1 * zb.z; c1[2 * h + 1].y += d1 * zb.w;
        }
    }
    float2* t0 = T + (((size_t)(2 * p + 0) * 64 + mu) * 64 + j) * 64 + s * 16;
    float2* t1 = T + (((size_t)(2 * p + 1) * 64 + mu) * 64 + j) * 64 + s * 16;
    #pragma unroll
    for (int k = 0; k < 16; k++) t0[k] = c0[k];
    #pragma unroll
    for (int k = 0; k < 16; k++) t1[k] = c1[k];
}

// Synthesis stage B: radix-8 x2 IDFT; float4 T staging; real + bias out.
__global__ __launch_bounds__(TPB) void k_synB(const float2* __restrict__ T,
                                              const float2* __restrict__ twi_g,
                                              const float* __restrict__ bias,
                                              float* __restrict__ yout,
                                              int Fo, int zo0) {
    __shared__ float2 sF[64 * 66];
    __shared__ float2 tw[64];
    int blk = blockIdx.x;
    int zo_l = blk >> 6, j = blk & 63;
    int zo_g = zo0 + zo_l;
    int o = zo_g % Fo;
    int tid = threadIdx.x;
    if (tid < 64) tw[tid] = twi_g[tid];
    const float4* src4 = (const float4*)(T + (size_t)zo_l * kCube + (size_t)j * 64);
    for (int i = tid; i < 2048; i += TPB) {
        int mu = i >> 5, half = i & 31;
        float4 v = src4[(size_t)mu * 2048 + half];
        sF[mu * 66 + 2 * half]     = make_float2(v.x, v.y);
        sF[mu * 66 + 2 * half + 1] = make_float2(v.z, v.w);
    }
    __syncthreads();
    float2 w8[8];
    #pragma unroll
    for (int k = 0; k < 8; k++) w8[k] = tw[k * 8];
    int r2 = tid >> 2, q = tid & 3;
    {   // dim-nu, complex in-place radix-8
        float2* mrow = sF + r2 * 66;
        #pragma unroll
        for (int half = 0; half < 2; half++) {
            int s = q + 4 * half;
            float2 f[8];
            #pragma unroll
            for (int p = 0; p < 8; p++) f[p] = mrow[8 * p + s];
            float2 ws = tw[s];
            float2 t = make_float2(1.f, 0.f);
            #pragma unroll
            for (int v = 0; v < 8; v++) {
                float re = 0, im = 0;
                #pragma unroll
                for (int p = 0; p < 8; p++) {
                    float2 w = w8[(v * p) & 7];
                    re += f[p].x * w.x - f[p].y * w.y;
                    im += f[p].x * w.y + f[p].y * w.x;
                }
                mrow[v * 8 + s] = make_float2(re * t.x - im * t.y, re * t.y + im * t.x);
                float tx = t.x * ws.x - t.y * ws.y;
                t.y = t.x * ws.y + t.y * ws.x; t.x = tx;
            }
        }
        float2 a[2][8];
        #pragma unroll
        for (int half = 0; half < 2; half++) {
            int v = q + 4 * half;
            #pragma unroll
            for (int s = 0; s < 8; s++) a[half][s] = mrow[v * 8 + s];
        }
        #pragma unroll
        for (int half = 0; half < 2; half++) {
            int v = q + 4 * half;
            #pragma unroll
            for (int u = 0; u < 8; u++) {
                float re = 0, im = 0;
                #pragma unroll
                for (int s = 0; s < 8; s++) {
                    float2 w = w8[(u * s) & 7];
                    re += a[half][s].x * w.x - a[half][s].y * w.y;
                    im += a[half][s].x * w.y + a[half][s].y * w.x;
                }
                mrow[8 * u + v] = make_float2(re, im);
            }
        }
    }
    __syncthreads();
    {   // dim-mu, per column c; real + bias out
        int c = r2;
        float bo = bias[o];
        float* dst = yout + ((size_t)zo_g * 64 + j) * 4096;
        #pragma unroll
        for (int half = 0; half < 2; half++) {
            int s = q + 4 * half;
            float2 f[8];
            #pragma unroll
            for (int p = 0; p < 8; p++) f[p] = sF[(8 * p + s) * 66 + c];
            float2 ws = tw[s];
            float2 t = make_float2(1.f, 0.f);
            #pragma unroll
            for (int v = 0; v < 8; v++) {
                float re = 0, im = 0;
                #pragma unroll
                for (int p = 0; p < 8; p++) {
                    float2 w = w8[(v * p) & 7];
                    re += f[p].x * w.x - f[p].y * w.y;
                    im += f[p].x * w.y + f[p].y * w.x;
                }
                sF[(v * 8 + s) * 66 + c] = make_float2(re * t.x - im * t.y,
                                                       re * t.y + im * t.x);
                float tx = t.x * ws.x - t.y * ws.y;
                t.y = t.x * ws.y + t.y * ws.x; t.x = tx;
            }
        }
        float2 a[2][8];
        #pragma unroll
        for (int half = 0; half < 2; half++) {
            int v = q + 4 * half;
            #pragma unroll
            for (int s = 0; s < 8; s++) a[half][s] = sF[(v * 8 + s) * 66 + c];
        }
        #pragma unroll
        for (int half = 0; half < 2; half++) {
            int v = q + 4 * half;
            #pragma unroll
            for (int u = 0; u < 8; u++) {
                float re = 0;
                #pragma unroll
                for (int s = 0; s < 8; s++) {
                    float2 w = w8[(u * s) & 7];
                    re += a[half][s].x * w.x - a[half][s].y * w.y;
                }
                dst[(8 * u + v) * 64 + c] = re + bo;
            }
        }
    }
}

__global__ void k_bn_stats(const float* __restrict__ y, float* __restrict__ stats, int Fo) {
    __shared__ float ss[TPB], sq[TPB];
    int o = blockIdx.y, chunk = blockIdx.x, tid = threadIdx.x;
    int base = chunk * 4096;
    int z = base >> 18, within = base & (kCube - 1);
    const float* p = y + ((size_t)(z * Fo + o) << 18) + within;
    float s = 0, q = 0;
    for (int k = 0; k < 16; k++) {
        float v = p[k * TPB + tid];
        s += v; q += v * v;
    }
    ss[tid] = s; sq[tid] = q;
    __syncthreads();
    for (int st = TPB / 2; st > 0; st >>= 1) {
        if (tid < st) { ss[tid] += ss[tid + st]; sq[tid] += sq[tid + st]; }
        __syncthreads();
    }
    if (tid == 0) {
        atomicAdd(&stats[o * 2], ss[0]);
        atomicAdd(&stats[o * 2 + 1], sq[0]);
    }
}

__global__ void k_final(const float* __restrict__ y, const float* __restrict__ stats,
                        const float* __restrict__ gamma, const float* __restrict__ beta,
                        float* __restrict__ out) {
    int t = blockIdx.x * TPB + threadIdx.x;
    if (t >= kB * kF2 * 4096) return;
    int zo = t >> 12, o = zo % kF2;
    const float inv = 1.0f / 524288.0f;
    float mean = stats[o * 2] * inv;
    float var = stats[o * 2 + 1] * inv - mean * mean;
    float rstd = rsqrtf(var + 1e-5f);
    float ga = gamma[o], be = beta[o];
    const float* p = y + (size_t)t * 64;
    float acc = 0;
    for (int g = 0; g < 64; g++) {
        float v = (p[g] - mean) * rstd * ga + be;
        acc += v > 0.f ? v : 0.f;
    }
    out[t] = acc * (1.0f / 64.0f);
}

// ---------------------------------------------------------------------------
extern "C" void kernel_launch(void* const* d_in, const int* in_sizes, int n_in,
                              void* d_out, int out_size, void* d_ws, size_t ws_size,
                              hipStream_t stream) {
    const float* x     = (const float*)d_in[0];
    const float* k1    = (const float*)d_in[1];
    const float* bias1 = (const float*)d_in[2];
    const float* g1    = (const float*)d_in[3];
    const float* be1   = (const float*)d_in[4];
    const float* k2    = (const float*)d_in[5];
    const float* bias2 = (const float*)d_in[6];
    const float* g2    = (const float*)d_in[7];
    const float* be2   = (const float*)d_in[8];
    const float* k3    = (const float*)d_in[9];
    const float* bias3 = (const float*)d_in[10];
    const float* g3    = (const float*)d_in[11];
    const float* be3   = (const float*)d_in[12];

    char* ws = (char*)d_ws;
    size_t off = 0;
    auto alloc = [&](size_t bytes) {
        size_t cur = off;
        off = (off + bytes + 255) & ~(size_t)255;
        return cur;
    };
    size_t o_const = alloc(g_tab.bytes);                       // 2.9 MB
    size_t o_dqz   = alloc((size_t)kNM * 64 * 64 * 4);         // 16.8 MB
    size_t o_dqtw  = alloc((size_t)64 * kNMN * 4);             // 11.2 MB
    size_t o_deT   = alloc((size_t)kNMN * 4);                  // 0.17 MB
    size_t o_khat  = alloc((size_t)kF1 * kF1 * 64 * 8);        // 1.8 MB
    size_t o_xf1   = alloc((size_t)kB * kF0 * 64 * 64 * 8);    // 0.2 MB
    size_t o_fh1   = alloc((size_t)kNM * kB * kF0 * 8);        // 0.05 MB
    size_t o_stats = alloc(2 * 64 * 4);
    size_t o_fh    = alloc((size_t)kB * kF1 * kNMN * 8);       // 42 MB (fh, then zs)
    size_t o_scr   = alloc((size_t)kFCH * kCube * 8);          // 50.3 MB (dtmp/xf/G/T)
    size_t o_cube  = alloc((size_t)kB * kF1 * kCube * 4);      // 126 MB
    if (off > ws_size) return;

    const float* cb = (const float*)(ws + o_const);
    const float2* twf = (const float2*)(cb + g_tab.o_twf);
    const float2* twi = (const float2*)(cb + g_tab.o_twi);
    const float* w_t = cb + g_tab.o_w;
    const float* etab = cb + g_tab.o_etab;
    const float* dehalf = etab + (size_t)(8 + 4) * kNMN;  // G_4 = E0^32 = d(pi/2)
    const int* lmn_l = (const int*)(cb + g_tab.o_lmnl);
    const int* lm_l = (const int*)(cb + g_tab.o_lml);

    float* dqz = (float*)(ws + o_dqz);
    float* dqtw = (float*)(ws + o_dqtw);
    float* deT = (float*)(ws + o_deT);
    float2* khat = (float2*)(ws + o_khat);
    float2* xf1 = (float2*)(ws + o_xf1);
    float2* fh1 = (float2*)(ws + o_fh1);
    float* stats = (float*)(ws + o_stats);
    float2* fh = (float2*)(ws + o_fh);
    float2* zsb = (float2*)(ws + o_fh);
    float* dtmp = (float*)(ws + o_scr);
    float2* Gb = (float2*)(ws + o_scr);
    float2* xfc = (float2*)(ws + o_scr);
    float2* Tb = (float2*)(ws + o_scr);
    float* cube = (float*)(ws + o_cube);

    hipMemcpyAsync(ws + o_const, g_tab.blob.data(), g_tab.bytes,
                   hipMemcpyHostToDevice, stream);
    hipMemsetAsync(dqz, 0, (size_t)kNM * 64 * 64 * 4, stream);
    k_gendqA<<<kLMAX * 64, TPB, 0, stream>>>(etab, dtmp);
    k_scat<<<kLMAX * 63, TPB, 0, stream>>>(dtmp, w_t, dqz, dqtw);
    k_transde<<<(kNMN + TPB - 1) / TPB, TPB, 0, stream>>>(dehalf, deT, lmn_l);

    const float S2S = 1.0f / sqrtf(64.0f * 3.0f * 1024.0f);
    const float SO3S = 1.0f / sqrtf(64.0f * 60.0f);
    auto blks = [](size_t n) { return (int)((n + TPB - 1) / TPB); };

    auto synth = [&](const float* bi, int Fo) {
        int planes = kB * Fo;
        for (int zo0 = 0; zo0 < planes; zo0 += kFCH) {
            int nzo = planes - zo0 < kFCH ? planes - zo0 : kFCH;
            k_synA<<<dim3(64, nzo / 2), TPB, 0, stream>>>(
                zsb + (size_t)zo0 * kNMN, dqz, Tb);
            k_synB<<<nzo * 64, TPB, 0, stream>>>(Tb, twi, bi, cube, Fo, zo0);
        }
    };
    auto bnstats = [&](int Fo) {
        hipMemsetAsync(stats, 0, 2 * 64 * 4, stream);
        k_bn_stats<<<dim3(128, Fo), TPB, 0, stream>>>(cube, stats, Fo);
    };

    // ---- Layer 1: S2 conv -> cube ----
    k_khat<<<blks(kF0 * kF1 * 64), TPB, 0, stream>>>(k1, khat, twf, kF0 * kF1 * 64, S2S);
    k_fft1<<<blks(kB * kF0 * 64 * 64), TPB, 0, stream>>>(x, xf1, twf);
    k_fh1<<<blks(kNM * kB * kF0), TPB, 0, stream>>>(xf1, dqtw, lm_l, fh1);
    k_zs1<<<blks((size_t)(kF1 / 6) * kNMN), TPB, 0, stream>>>(fh1, khat, dehalf, lmn_l, zsb);
    synth(bias1, kF1);
    bnstats(kF1);

    // ---- Layers 2 & 3: SO3 conv; fft2 applies previous layer's BN+ReLU ----
    for (int layer = 2; layer <= 3; layer++) {
        int Fo = (layer == 2) ? kF1 : kF2;
        const float* kk = (layer == 2) ? k2 : k3;
        const float* bi = (layer == 2) ? bias2 : bias3;
        const float* gp = (layer == 2) ? g1 : g2;
        const float* bp = (layer == 2) ? be1 : be2;
        k_khat<<<blks(kF1 * Fo * 64), TPB, 0, stream>>>(kk, khat, twf, kF1 * Fo * 64, SO3S);
        for (int zf0 = 0; zf0 < kB * kF1; zf0 += kFCH) {
            int nzf = kB * kF1 - zf0 < kFCH ? kB * kF1 - zf0 : kFCH;
            k_fft2<<<nzf * 64, TPB, 0, stream>>>(cube + (size_t)zf0 * kCube, xfc,
                                                 twf, stats, gp, bp, zf0);
            k_fh3<<<blks((size_t)nzf * kNMN), TPB, 0, stream>>>(
                xfc, dqtw, lmn_l, fh + (size_t)zf0 * kNMN, nzf);
        }
        k_G<<<blks((size_t)kB * kF1 * kNMN), TPB, 0, stream>>>(fh, deT, lmn_l, Gb, kF1);
        k_zs<<<blks((size_t)(Fo / 6) * kNMN), TPB, 0, stream>>>(Gb, khat, lmn_l, zsb, kF1, Fo);
        synth(bi, Fo);
        bnstats(Fo);
        if (layer == 3)
            k_final<<<blks(kB * kF2 * 4096), TPB, 0, stream>>>(cube, stats, g3, be3, (float*)d_out);
    }
}